// Round 3
// baseline (119.974 us; speedup 1.0000x reference)
//
#include <hip/hip_runtime.h>

#define KS 7
#define NG 16
#define PAD 3
#define NB 4
#define NC 64
#define NH 128
#define NW 128
#define HW (NH*NW)
#define NR 16
#define CG 4            // NC/NG
#define TILE 8
#define HALO 14         // TILE + 2*PAD
#define KK 49           // KS*KS
#define WPB 4           // waves (= groups) per block

// ---------------- Kernel A: red[b][pix][r] = relu(w_reduce @ x + b_reduce) ----
__global__ __launch_bounds__(256)
void red_kernel(const float* __restrict__ x,
                const float* __restrict__ w_reduce,
                const float* __restrict__ b_reduce,
                float* __restrict__ red) {
    __shared__ float wT[NC][NR];           // transposed: wT[c][r]
    const int t = threadIdx.x;
    #pragma unroll
    for (int e = 0; e < 4; ++e) {
        int i = t * 4 + e;                 // 0..1023, coalesced
        wT[i & 63][i >> 6] = w_reduce[i];  // w_reduce[r*64+c] -> wT[c][r]
    }
    __syncthreads();

    const int p   = blockIdx.x * 256 + t;  // 0..65535
    const int b   = p >> 14;               // /16384
    const int pix = p & 16383;

    float acc[NR];
    #pragma unroll
    for (int r = 0; r < NR; ++r) acc[r] = b_reduce[r];

    const float* xp = x + (size_t)b * (NC * HW) + pix;
    #pragma unroll 16
    for (int c = 0; c < NC; ++c) {
        float xv = xp[(size_t)c * HW];     // coalesced across lanes
        const float4* wv = (const float4*)&wT[c][0];     // broadcast reads
        float4 w0 = wv[0], w1 = wv[1], w2 = wv[2], w3 = wv[3];
        acc[0]  = fmaf(w0.x, xv, acc[0]);  acc[1]  = fmaf(w0.y, xv, acc[1]);
        acc[2]  = fmaf(w0.z, xv, acc[2]);  acc[3]  = fmaf(w0.w, xv, acc[3]);
        acc[4]  = fmaf(w1.x, xv, acc[4]);  acc[5]  = fmaf(w1.y, xv, acc[5]);
        acc[6]  = fmaf(w1.z, xv, acc[6]);  acc[7]  = fmaf(w1.w, xv, acc[7]);
        acc[8]  = fmaf(w2.x, xv, acc[8]);  acc[9]  = fmaf(w2.y, xv, acc[9]);
        acc[10] = fmaf(w2.z, xv, acc[10]); acc[11] = fmaf(w2.w, xv, acc[11]);
        acc[12] = fmaf(w3.x, xv, acc[12]); acc[13] = fmaf(w3.y, xv, acc[13]);
        acc[14] = fmaf(w3.z, xv, acc[14]); acc[15] = fmaf(w3.w, xv, acc[15]);
    }
    #pragma unroll
    for (int r = 0; r < NR; ++r) acc[r] = fmaxf(acc[r], 0.f);

    float4* rp = (float4*)(red + (size_t)p * NR);        // 64B/lane, coalesced
    rp[0] = make_float4(acc[0],  acc[1],  acc[2],  acc[3]);
    rp[1] = make_float4(acc[4],  acc[5],  acc[6],  acc[7]);
    rp[2] = make_float4(acc[8],  acc[9],  acc[10], acc[11]);
    rp[3] = make_float4(acc[12], acc[13], acc[14], acc[15]);
}

// ---------------- Kernel B: span conv -> softmax -> involution gather ---------
// 256-thread blocks = 4 waves; wave wv handles group blockIdx.y*4+wv on the
// same 8x8 tile. g is wave-uniform -> w_span/b_span stay on the scalar pipe.
__global__ __launch_bounds__(256, 6)
void invol_kernel(const float* __restrict__ x,
                  const float* __restrict__ w_span,
                  const float* __restrict__ b_span,
                  const float* __restrict__ red,
                  float* __restrict__ out) {
    __shared__ float4 xs[WPB][HALO * HALO];   // 4 * 196 * 16B = 12544 B

    const int t    = threadIdx.x;
    const int lane = t & 63;
    const int wv   = __builtin_amdgcn_readfirstlane(t >> 6);   // 0..3, SGPR
    const int ph = lane >> 3, pw = lane & 7;
    const int h0 = (blockIdx.x >> 4) * TILE;
    const int w0 = (blockIdx.x & 15) * TILE;
    const int g  = blockIdx.y * WPB + wv;      // SGPR
    const int b  = blockIdx.z;

    // ---- stage: wave wv stages its group's 4 channels as float4 per position
    const float* xb = x + (size_t)(b * NC + g * CG) * HW;
    #pragma unroll
    for (int it = 0; it < 4; ++it) {
        int idx = lane + it * 64;              // 0..255, need < 196
        if (idx < HALO * HALO) {
            int hh = idx / HALO;
            int ww = idx - hh * HALO;
            int gh = h0 + hh - PAD;
            int gw = w0 + ww - PAD;
            float4 v = make_float4(0.f, 0.f, 0.f, 0.f);
            if ((unsigned)gh < NH && (unsigned)gw < NW) {
                const float* p = xb + gh * NW + gw;
                v.x = p[0];
                v.y = p[HW];
                v.z = p[2 * HW];
                v.w = p[3 * HW];
            }
            xs[wv][idx] = v;                   // consecutive-lane float4: conflict-free
        }
    }
    __syncthreads();

    // ---- reduced features: 16 contiguous floats per (b,pixel) ----
    const int pixel = (h0 + ph) * NW + (w0 + pw);
    const float4* rp = (const float4*)(red + ((size_t)b * HW + pixel) * NR);
    float4 q0 = rp[0], q1 = rp[1], q2 = rp[2], q3 = rp[3];
    float rv[NR] = {q0.x, q0.y, q0.z, q0.w, q1.x, q1.y, q1.z, q1.w,
                    q2.x, q2.y, q2.z, q2.w, q3.x, q3.y, q3.z, q3.w};

    // ---- span conv fused with exp + sum (no max-sub: logits << 88) ----
    const float* wg = w_span + (size_t)g * (KK * NR);   // scalar loads
    const float* bg = b_span + (size_t)g * KK;
    float s[KK];
    float sum = 0.f;
    #pragma unroll
    for (int k = 0; k < KK; ++k) {
        float a = bg[k];
        #pragma unroll
        for (int r = 0; r < NR; ++r)
            a = fmaf(wg[k * NR + r], rv[r], a);
        float e = __expf(a);
        s[k] = e;
        sum += e;
    }
    float inv = 1.0f / sum;

    // ---- involution gather: 49 taps x 4 channels via ds_read_b128 ----
    float a0 = 0.f, a1 = 0.f, a2 = 0.f, a3 = 0.f;
    #pragma unroll
    for (int i = 0; i < KS; ++i) {
        #pragma unroll
        for (int j = 0; j < KS; ++j) {
            float4 v = xs[wv][(ph + i) * HALO + (pw + j)];
            float wt = s[i * KS + j];
            a0 = fmaf(wt, v.x, a0);
            a1 = fmaf(wt, v.y, a1);
            a2 = fmaf(wt, v.z, a2);
            a3 = fmaf(wt, v.w, a3);
        }
    }

    const int h = h0 + ph, w = w0 + pw;
    size_t ob = ((size_t)(b * NC + g * CG) * NH + h) * NW + w;
    out[ob]          = a0 * inv;
    out[ob + HW]     = a1 * inv;
    out[ob + 2 * HW] = a2 * inv;
    out[ob + 3 * HW] = a3 * inv;
}

extern "C" void kernel_launch(void* const* d_in, const int* in_sizes, int n_in,
                              void* d_out, int out_size, void* d_ws, size_t ws_size,
                              hipStream_t stream) {
    const float* x        = (const float*)d_in[0];
    const float* w_reduce = (const float*)d_in[1];
    const float* b_reduce = (const float*)d_in[2];
    const float* w_span   = (const float*)d_in[3];
    const float* b_span   = (const float*)d_in[4];
    float* out = (float*)d_out;
    float* red = (float*)d_ws;               // 4 MB (B*H*W*16 fp32)

    red_kernel<<<dim3(NB * HW / 256), 256, 0, stream>>>(x, w_reduce, b_reduce, red);

    dim3 gridB(256, NG / WPB, NB);           // (tiles, group-quads, batch) = 4096 blocks
    invol_kernel<<<gridB, 256, 0, stream>>>(x, w_span, b_span, red, out);
}

// Round 4
// 61.973 us; speedup vs baseline: 1.9359x; 1.9359x over previous
//
#include <hip/hip_runtime.h>

#define KS 7
#define NG 16
#define PAD 3
#define NB 4
#define NC 64
#define NH 128
#define NW 128
#define HW (NH*NW)
#define NR 16
#define CG 4            // NC/NG
#define TILE 8
#define HALO 14         // TILE + 2*PAD
#define KK 49           // KS*KS
#define WPB 4           // waves (= groups) per block

// ---------------- Kernel A: red[b][pix][r] = relu(w_reduce @ x + b_reduce) ----
__global__ __launch_bounds__(256)
void red_kernel(const float* __restrict__ x,
                const float* __restrict__ w_reduce,
                const float* __restrict__ b_reduce,
                float* __restrict__ red) {
    __shared__ float wT[NC][NR];           // transposed: wT[c][r]
    const int t = threadIdx.x;
    #pragma unroll
    for (int e = 0; e < 4; ++e) {
        int i = t * 4 + e;                 // 0..1023, coalesced
        wT[i & 63][i >> 6] = w_reduce[i];  // w_reduce[r*64+c] -> wT[c][r]
    }
    __syncthreads();

    const int p   = blockIdx.x * 256 + t;  // 0..65535
    const int b   = p >> 14;               // /16384
    const int pix = p & 16383;

    float acc[NR];
    #pragma unroll
    for (int r = 0; r < NR; ++r) acc[r] = b_reduce[r];

    const float* xp = x + (size_t)b * (NC * HW) + pix;
    #pragma unroll 16
    for (int c = 0; c < NC; ++c) {
        float xv = xp[(size_t)c * HW];     // coalesced across lanes
        const float4* wv = (const float4*)&wT[c][0];     // broadcast reads
        float4 w0 = wv[0], w1 = wv[1], w2 = wv[2], w3 = wv[3];
        acc[0]  = fmaf(w0.x, xv, acc[0]);  acc[1]  = fmaf(w0.y, xv, acc[1]);
        acc[2]  = fmaf(w0.z, xv, acc[2]);  acc[3]  = fmaf(w0.w, xv, acc[3]);
        acc[4]  = fmaf(w1.x, xv, acc[4]);  acc[5]  = fmaf(w1.y, xv, acc[5]);
        acc[6]  = fmaf(w1.z, xv, acc[6]);  acc[7]  = fmaf(w1.w, xv, acc[7]);
        acc[8]  = fmaf(w2.x, xv, acc[8]);  acc[9]  = fmaf(w2.y, xv, acc[9]);
        acc[10] = fmaf(w2.z, xv, acc[10]); acc[11] = fmaf(w2.w, xv, acc[11]);
        acc[12] = fmaf(w3.x, xv, acc[12]); acc[13] = fmaf(w3.y, xv, acc[13]);
        acc[14] = fmaf(w3.z, xv, acc[14]); acc[15] = fmaf(w3.w, xv, acc[15]);
    }
    #pragma unroll
    for (int r = 0; r < NR; ++r) acc[r] = fmaxf(acc[r], 0.f);

    float4* rp = (float4*)(red + (size_t)p * NR);        // 64B/lane, coalesced
    rp[0] = make_float4(acc[0],  acc[1],  acc[2],  acc[3]);
    rp[1] = make_float4(acc[4],  acc[5],  acc[6],  acc[7]);
    rp[2] = make_float4(acc[8],  acc[9],  acc[10], acc[11]);
    rp[3] = make_float4(acc[12], acc[13], acc[14], acc[15]);
}

// ---------------- Kernel B: fully fused per-tap span->exp->gather -------------
// 256-thread blocks = 4 waves; wave wv handles group blockIdx.y*4+wv on the
// same 8x8 tile. g is wave-uniform -> w_span/b_span via scalar loads.
// Softmax normalization is deferred: out = (sum_k e_k * x_k) / (sum_k e_k),
// so NO 49-element per-thread array exists -> no spills.
__global__ __launch_bounds__(256, 4)
void invol_kernel(const float* __restrict__ x,
                  const float* __restrict__ w_span,
                  const float* __restrict__ b_span,
                  const float* __restrict__ red,
                  float* __restrict__ out) {
    __shared__ float4 xs[WPB][HALO * HALO];   // 4 * 196 * 16B = 12544 B

    const int t    = threadIdx.x;
    const int lane = t & 63;
    const int wv   = __builtin_amdgcn_readfirstlane(t >> 6);   // 0..3, SGPR
    const int ph = lane >> 3, pw = lane & 7;
    const int h0 = (blockIdx.x >> 4) * TILE;
    const int w0 = (blockIdx.x & 15) * TILE;
    const int g  = blockIdx.y * WPB + wv;      // SGPR
    const int b  = blockIdx.z;

    // ---- stage: wave wv stages its group's 4 channels as float4 per position
    const float* xb = x + (size_t)(b * NC + g * CG) * HW;
    #pragma unroll
    for (int it = 0; it < 4; ++it) {
        int idx = lane + it * 64;              // 0..255, need < 196
        if (idx < HALO * HALO) {
            int hh = idx / HALO;
            int ww = idx - hh * HALO;
            int gh = h0 + hh - PAD;
            int gw = w0 + ww - PAD;
            float4 v = make_float4(0.f, 0.f, 0.f, 0.f);
            if ((unsigned)gh < NH && (unsigned)gw < NW) {
                const float* p = xb + gh * NW + gw;
                v.x = p[0];
                v.y = p[HW];
                v.z = p[2 * HW];
                v.w = p[3 * HW];
            }
            xs[wv][idx] = v;
        }
    }
    __syncthreads();

    // ---- reduced features: 16 contiguous floats per (b,pixel) ----
    const int pixel = (h0 + ph) * NW + (w0 + pw);
    const float4* rp = (const float4*)(red + ((size_t)b * HW + pixel) * NR);
    float4 q0 = rp[0], q1 = rp[1], q2 = rp[2], q3 = rp[3];
    float rv[NR] = {q0.x, q0.y, q0.z, q0.w, q1.x, q1.y, q1.z, q1.w,
                    q2.x, q2.y, q2.z, q2.w, q3.x, q3.y, q3.z, q3.w};

    const float* wg = w_span + (size_t)g * (KK * NR);   // scalar loads (g SGPR)
    const float* bg = b_span + (size_t)g * KK;

    // ---- fused per-tap: logit -> exp -> weighted gather ----
    float sum = 0.f;
    float a0 = 0.f, a1 = 0.f, a2 = 0.f, a3 = 0.f;
    #pragma unroll
    for (int i = 0; i < KS; ++i) {
        #pragma unroll
        for (int j = 0; j < KS; ++j) {
            const int k = i * KS + j;
            const float* wk = wg + k * NR;
            // 4 partial sums: dependency chain 4 deep instead of 16
            float p0 = bg[k], p1 = 0.f, p2 = 0.f, p3 = 0.f;
            #pragma unroll
            for (int r = 0; r < NR; r += 4) {
                p0 = fmaf(wk[r + 0], rv[r + 0], p0);
                p1 = fmaf(wk[r + 1], rv[r + 1], p1);
                p2 = fmaf(wk[r + 2], rv[r + 2], p2);
                p3 = fmaf(wk[r + 3], rv[r + 3], p3);
            }
            float e = __expf((p0 + p1) + (p2 + p3));   // logits are O(1): no max-sub
            sum += e;
            float4 v = xs[wv][(ph + i) * HALO + (pw + j)];
            a0 = fmaf(e, v.x, a0);
            a1 = fmaf(e, v.y, a1);
            a2 = fmaf(e, v.z, a2);
            a3 = fmaf(e, v.w, a3);
        }
    }
    float inv = 1.0f / sum;

    const int h = h0 + ph, w = w0 + pw;
    size_t ob = ((size_t)(b * NC + g * CG) * NH + h) * NW + w;
    out[ob]          = a0 * inv;
    out[ob + HW]     = a1 * inv;
    out[ob + 2 * HW] = a2 * inv;
    out[ob + 3 * HW] = a3 * inv;
}

extern "C" void kernel_launch(void* const* d_in, const int* in_sizes, int n_in,
                              void* d_out, int out_size, void* d_ws, size_t ws_size,
                              hipStream_t stream) {
    const float* x        = (const float*)d_in[0];
    const float* w_reduce = (const float*)d_in[1];
    const float* b_reduce = (const float*)d_in[2];
    const float* w_span   = (const float*)d_in[3];
    const float* b_span   = (const float*)d_in[4];
    float* out = (float*)d_out;
    float* red = (float*)d_ws;               // 4 MB (B*H*W*16 fp32)

    red_kernel<<<dim3(NB * HW / 256), 256, 0, stream>>>(x, w_reduce, b_reduce, red);

    dim3 gridB(256, NG / WPB, NB);           // (tiles, group-quads, batch) = 4096 blocks
    invol_kernel<<<gridB, 256, 0, stream>>>(x, w_span, b_span, red, out);
}